// Round 4
// baseline (1011.190 us; speedup 1.0000x reference)
//
#include <hip/hip_runtime.h>
#include <stdint.h>

typedef unsigned short u16;
typedef __attribute__((ext_vector_type(8))) short short8;
typedef __attribute__((ext_vector_type(8))) u16 u16x8;
typedef __attribute__((ext_vector_type(4))) u16 u16x4;
typedef __attribute__((ext_vector_type(4))) float f32x4;

#define E_TOT 30000
#define TL    3712     // 29*128
#define RADN  2304
#define BM    256
#define BK    64

// PERM: m-major reorder of the 29 (l,m) coefficients
__constant__ int d_PERM[29] = {0,2,6,11,16,21,26, 3,7,12,17,22,27, 1,5,10,15,20,25,
                               8,13,18,23,28, 4,9,14,19,24};
__constant__ int d_RADCOL[29] = {0,1,2,3,4,5,6, 7,8,9,10,11,12, 7,8,9,10,11,12,
                                 13,14,15,16,17, 13,14,15,16,17};

__device__ __forceinline__ u16 f2bf(float f){
  union { float f; uint32_t u; } v; v.f = f;
  return (u16)((v.u + 0x7FFFu + ((v.u >> 16) & 1u)) >> 16);   // RNE
}
__device__ __forceinline__ float bf2f(u16 u){
  union { uint32_t u; float f; } v; v.u = ((uint32_t)u) << 16;
  return v.f;
}
__device__ __forceinline__ void gl_lds16(const void* g, void* l){
  __builtin_amdgcn_global_load_lds((const __attribute__((address_space(1))) void*)g,
                                   (__attribute__((address_space(3))) void*)l, 16, 0, 0);
}

// ---------------------------------------------------------------- weights
__global__ void k_build_w(const float* __restrict__ w0, const float* __restrict__ w1,
                          const float* __restrict__ w2,
                          u16* __restrict__ W0, u16* __restrict__ W1, u16* __restrict__ W2){
  int idx = blockIdx.x * 256 + threadIdx.x;
  if (idx < 1024*896){
    W0[idx] = (idx < 896*896) ? f2bf(w0[idx]) : (u16)0;
    return;
  }
  idx -= 1024*896;
  if (idx < 1536*1536){
    const int half = 768;
    int o = idx / 1536, i2 = idx - o*1536;
    float v;
    if (o < half) v = (i2 < half) ? w1[o*half + i2] : -w1[(half+o)*half + (i2-half)];
    else { int op = o - half;
           v = (i2 < half) ? w1[(half+op)*half + i2] : w1[op*half + (i2-half)]; }
    W1[idx] = f2bf(v);
    return;
  }
  idx -= 1536*1536;
  if (idx < 1280*1280){
    const int half = 640;
    int o = idx / 1280, i2 = idx - o*1280;
    float v;
    if (o < half) v = (i2 < half) ? w2[o*half + i2] : -w2[(half+o)*half + (i2-half)];
    else { int op = o - half;
           v = (i2 < half) ? w2[(half+op)*half + i2] : w2[op*half + (i2-half)]; }
    W2[idx] = f2bf(v);
  }
}

// ---------------------------------------------------------------- h = silu(LN(xe@w1^T+b1))
__global__ __launch_bounds__(256) void k_h(const float* __restrict__ xe,
    const float* __restrict__ w1, const float* __restrict__ b1,
    const float* __restrict__ g, const float* __restrict__ beta,
    u16* __restrict__ hout){
  __shared__ float sxe[16*128];
  int tid = threadIdx.x;
  int eb = blockIdx.x * 16;
  #pragma unroll
  for (int q = 0; q < 2; q++){
    int off = q*1024 + tid*4;
    *(f32x4*)&sxe[off] = *(const f32x4*)&xe[(long)eb*128 + off];
  }
  __syncthreads();
  int el = tid >> 4, s = tid & 15;
  float acc[8];
  #pragma unroll
  for (int q = 0; q < 8; q++) acc[q] = 0.f;
  const float* xr = &sxe[el*128];
  for (int c4 = 0; c4 < 32; c4++){
    f32x4 x = *(const f32x4*)&xr[c4*4];
    #pragma unroll
    for (int q = 0; q < 8; q++){
      f32x4 w = *(const f32x4*)&w1[(s + 16*q)*128 + c4*4];
      acc[q] += x[0]*w[0] + x[1]*w[1] + x[2]*w[2] + x[3]*w[3];
    }
  }
  float sum = 0.f, ss = 0.f;
  #pragma unroll
  for (int q = 0; q < 8; q++){
    acc[q] += b1[s + 16*q];
    sum += acc[q]; ss += acc[q]*acc[q];
  }
  #pragma unroll
  for (int m = 1; m < 16; m <<= 1){ sum += __shfl_xor(sum, m); ss += __shfl_xor(ss, m); }
  float mu = sum * (1.f/128.f);
  float var = ss * (1.f/128.f) - mu*mu;
  float rs = rsqrtf(var + 1e-5f);
  int e = eb + el;
  #pragma unroll
  for (int q = 0; q < 8; q++){
    int j = s + 16*q;
    float v = (acc[q] - mu) * rs * g[j] + beta[j];
    v = v / (1.f + expf(-v));                 // silu
    hout[(long)e*128 + j] = f2bf(v);
  }
}

// ---------------------------------------------------------------- rad = h @ w2^T + b2 (bf16)
__global__ __launch_bounds__(256) void k_rad(const u16* __restrict__ h,
    const float* __restrict__ w2, const float* __restrict__ b2,
    u16* __restrict__ rad){
  __shared__ u16 sA[64*136];
  __shared__ u16 sB[64*136];
  int tid = threadIdx.x;
  int mb = blockIdx.x * 64, nb = blockIdx.y * 64;
  #pragma unroll
  for (int q = 0; q < 4; q++){
    int ch = q*256 + tid;
    int row = ch >> 4, col = (ch & 15) * 8;
    int er = mb + row; if (er > E_TOT-1) er = E_TOT-1;
    *(u16x8*)&sA[row*136 + col] = *(const u16x8*)&h[(long)er*128 + col];
  }
  #pragma unroll
  for (int q = 0; q < 8; q++){
    int ch = q*256 + tid;
    int row = ch >> 5, col = (ch & 31) * 4;
    f32x4 v = *(const f32x4*)&w2[(long)(nb + row)*128 + col];
    u16x4 o; o[0]=f2bf(v[0]); o[1]=f2bf(v[1]); o[2]=f2bf(v[2]); o[3]=f2bf(v[3]);
    *(u16x4*)&sB[row*136 + col] = o;
  }
  __syncthreads();
  int wid = tid >> 6, l = tid & 63;
  int lr = l & 15, lh = l >> 4;
  f32x4 acc[4];
  #pragma unroll
  for (int mi = 0; mi < 4; mi++){ acc[mi][0]=0;acc[mi][1]=0;acc[mi][2]=0;acc[mi][3]=0; }
  #pragma unroll
  for (int kk = 0; kk < 4; kk++){
    int kc = kk*32 + lh*8;
    short8 b = *(short8*)&sB[(wid*16 + lr)*136 + kc];
    #pragma unroll
    for (int mi = 0; mi < 4; mi++){
      short8 a = *(short8*)&sA[(mi*16 + lr)*136 + kc];
      acc[mi] = __builtin_amdgcn_mfma_f32_16x16x32_bf16(a, b, acc[mi], 0, 0, 0);
    }
  }
  #pragma unroll
  for (int mi = 0; mi < 4; mi++){
    #pragma unroll
    for (int q = 0; q < 4; q++){
      int er = mb + mi*16 + lh*4 + q;
      if (er < E_TOT){
        int nc = nb + wid*16 + lr;
        rad[(long)er*RADN + nc] = f2bf(acc[mi][q] + b2[nc]);
      }
    }
  }
}

// ---------------------------------------------------------------- t[e, r*128+c] = xm * rad
__global__ void k_t(const float* __restrict__ xemb, const u16* __restrict__ rad,
                    u16* __restrict__ t){
  long idx = (long)blockIdx.x * 256 + threadIdx.x;   // one 8-elem chunk
  int c8 = (int)(idx & 15);
  long tmp = idx >> 4;
  int r = (int)(tmp % 29);
  int e = (int)(tmp / 29);
  if (e >= E_TOT) return;
  int c = c8 * 8;
  const float* xr = &xemb[((long)e*29 + d_PERM[r])*128 + c];
  const u16* rr = &rad[(long)e*RADN + d_RADCOL[r]*128 + c];
  f32x4 x0 = *(const f32x4*)xr;
  f32x4 x1 = *(const f32x4*)(xr + 4);
  u16x8 rv = *(const u16x8*)rr;
  u16x8 o;
  o[0]=f2bf(x0[0]*bf2f(rv[0])); o[1]=f2bf(x0[1]*bf2f(rv[1]));
  o[2]=f2bf(x0[2]*bf2f(rv[2])); o[3]=f2bf(x0[3]*bf2f(rv[3]));
  o[4]=f2bf(x1[0]*bf2f(rv[4])); o[5]=f2bf(x1[1]*bf2f(rv[5]));
  o[6]=f2bf(x1[2]*bf2f(rv[6])); o[7]=f2bf(x1[3]*bf2f(rv[7]));
  *(u16x8*)&t[idx*8] = o;
}

// ---------------------------------------------------------------- 8-phase 256x256 GEMM
// Stage one half-tile s of K-tile kb into LDS (pre-swizzled global src):
// s=0: A rows{0-63,128-191}, s=1: B rows{+0..31 per 64-grp}, s=2: B rows{+32..63}, s=3: A rows{64-127,192-255}
__device__ __forceinline__ void stage_half(int s, const u16* __restrict__ A,
    const u16* __restrict__ Wg, int K, int kbase, int mrow, int ncol,
    int wid, int lane, u16* dstA, u16* dstB, int kb)
{
  #pragma unroll
  for (int j = 0; j < 2; j++){
    int CH = (wid*2 + j)*64 + lane;          // chunk index, 1024 x 16B per half-tile
    int c16 = CH & 7;
    if (s == 0 || s == 3){
      int qm = (s == 3) ? 1 : 0;
      int ra = ((CH >> 9) << 7) + qm*64 + ((CH >> 3) & 63);
      long grow = mrow + ra; if (grow > (long)(E_TOT-1)) grow = (long)(E_TOT-1);
      const u16* src = A + grow*(long)TL + (kbase + kb*64 + ((c16 ^ (ra & 7)) << 3));
      gl_lds16(src, dstA + ra*64 + c16*8);
    } else {
      int qn = (s == 2) ? 1 : 0;
      int rb = ((CH >> 8) << 6) + qn*32 + ((CH >> 3) & 31);
      const u16* src = Wg + (long)(ncol + rb)*K + (kb*64 + ((c16 ^ (rb & 7)) << 3));
      gl_lds16(src, dstB + rb*64 + c16*8);
    }
  }
}

#define WVM4 asm volatile("s_waitcnt vmcnt(4)" ::: "memory");
#define WVM2 asm volatile("s_waitcnt vmcnt(2)" ::: "memory");
#define WVM0 asm volatile("s_waitcnt vmcnt(0)" ::: "memory");
#define BARR __builtin_amdgcn_s_barrier();
#define SB0  __builtin_amdgcn_sched_barrier(0);
#define LGKM asm volatile("s_waitcnt lgkmcnt(0)" ::: "memory");

// read A-half QM into af (8 x ds_read_b128)
#define READ_A(buf, QM)                                                       \
  _Pragma("unroll")                                                           \
  for (int i = 0; i < 4; i++){                                                \
    _Pragma("unroll")                                                         \
    for (int ks = 0; ks < 2; ks++)                                            \
      af[i][ks] = *(const short8*)&sA[buf][(wr*128 + (QM)*64 + i*16 + lr)*64  \
                                           + ((ks*32 + lh*8) ^ swz)];         \
  }
// read B-half QN into dst (4 x ds_read_b128)
#define READ_B(dst, buf, QN)                                                  \
  _Pragma("unroll")                                                           \
  for (int j = 0; j < 2; j++){                                                \
    _Pragma("unroll")                                                         \
    for (int ks = 0; ks < 2; ks++)                                            \
      dst[j][ks] = *(const short8*)&sB[buf][(wc*64 + (QN)*32 + j*16 + lr)*64  \
                                            + ((ks*32 + lh*8) ^ swz)];        \
  }
// 16 MFMA for quadrant (QM,QN) using af x bfr
#define MFMA16(QM, QN, bfr)                                                   \
  __builtin_amdgcn_s_setprio(1);                                              \
  _Pragma("unroll")                                                           \
  for (int i = 0; i < 4; i++){                                                \
    _Pragma("unroll")                                                         \
    for (int j = 0; j < 2; j++){                                              \
      _Pragma("unroll")                                                       \
      for (int ks = 0; ks < 2; ks++)                                          \
        acc[(QM)*4+i][(QN)*2+j] = __builtin_amdgcn_mfma_f32_16x16x32_bf16(    \
            af[i][ks], bfr[j][ks], acc[(QM)*4+i][(QN)*2+j], 0, 0, 0);         \
    }                                                                         \
  }                                                                           \
  __builtin_amdgcn_s_setprio(0);                                              \
  SB0

#define STAGE(S, T) stage_half(S, A, Wg, K, kbase, mrow, ncol, wid, lane,     \
                               sA[(T)&1], sB[(T)&1], T); SB0

// One K-tile, m201-style phases: [reads][stage][vmcnt(4)][barrier][lgkm(0)][MFMA].
// Stage order for tile t+1: (B0,A0,B1,A1); each phase's vmcnt(4) retires exactly
// the unit the NEXT phase reads (queue never exceeds 6 before the wait).
#define TILE_BODY(P, BCUR, BNXT)                                              \
  READ_A(P, 0)                                                                \
  STAGE(1, t+1)                                                               \
  SB0 WVM4 BARR LGKM SB0                                                      \
  MFMA16(0,0,BCUR)                                                            \
  READ_B(b1, P, 1)                                                            \
  STAGE(0, t+1)                                                               \
  SB0 WVM4 BARR LGKM SB0                                                      \
  MFMA16(0,1,b1)                                                              \
  READ_A(P, 1)                                                                \
  STAGE(2, t+1)                                                               \
  SB0 WVM4 BARR LGKM SB0                                                      \
  MFMA16(1,1,b1)                                                              \
  READ_B(BNXT, (P)^1, 0)                                                      \
  STAGE(3, t+1)                                                               \
  SB0 WVM4 BARR LGKM SB0                                                      \
  MFMA16(1,0,BCUR)

// grid: 1770 blocks of 512 threads; 0..471 -> W0(K=896), 472..1179 -> W1(1536),
// 1180..1769 -> W2(1280). nbase == kbase for this problem. nkt is even for all.
__global__ __launch_bounds__(512, 2) void k_gemm8(
    const u16* __restrict__ A,
    const u16* __restrict__ W0, const u16* __restrict__ W1, const u16* __restrict__ W2,
    const float* __restrict__ bias0,
    float* __restrict__ out)
{
  __shared__ u16 sA[2][BM*BK];   // 2 x 32 KiB, swizzled (chunk ^= row&7)
  __shared__ u16 sB[2][BM*BK];   // 2 x 32 KiB

  // bijective XCD swizzle over 1770 blocks, 8 XCDs (1770 = 8*221 + 2)
  int orig = blockIdx.x;
  int xcd = orig & 7, idxs = orig >> 3;
  int wgid = (xcd < 2 ? xcd*222 : 444 + (xcd-2)*221) + idxs;

  int ntn, K, kbase, nvalid, base;
  const u16* Wg; const float* bias = nullptr;
  if (wgid < 472)      { base=0;    ntn=4; K=896;  kbase=0;    nvalid=896;  Wg=W0; bias=bias0; }
  else if (wgid < 1180){ base=472;  ntn=6; K=1536; kbase=896;  nvalid=1536; Wg=W1; }
  else                 { base=1180; ntn=5; K=1280; kbase=2432; nvalid=1280; Wg=W2; }
  int local = wgid - base;
  int ncol = (local % ntn) * 256;
  int mrow = (local / ntn) * 256;
  int nkt  = K >> 6;

  int tid = threadIdx.x;
  int lane = tid & 63, wid = tid >> 6;
  int wr = wid >> 2, wc = wid & 3;     // wave grid 2(M) x 4(N); wave tile 128 x 64
  int lr = lane & 15, lh = lane >> 4;
  int swz = (lane & 7) << 3;           // read-side XOR (u16 units); row&7 == lane&7

  f32x4 acc[8][4];
  #pragma unroll
  for (int i = 0; i < 8; i++)
    #pragma unroll
    for (int j = 0; j < 4; j++){ acc[i][j][0]=0;acc[i][j][1]=0;acc[i][j][2]=0;acc[i][j][3]=0; }

  short8 af[4][2];     // current A-half fragments
  short8 b1[2][2];     // B-half 1 fragments
  short8 b0A[2][2];    // B-half 0, even-tile set
  short8 b0B[2][2];    // B-half 0, odd-tile set

  // prologue: stage tile 0's units in order (B0,A0,B1,A1) -> buf 0
  STAGE(1, 0) STAGE(0, 0) STAGE(2, 0) STAGE(3, 0)
  SB0 WVM4 BARR SB0                    // B0,A0 of tile 0 resident (all waves)
  READ_B(b0A, 0, 0)

  int t = 0;
  for (int u = 0; u < (nkt >> 1) - 1; ++u){
    TILE_BODY(0, b0A, b0B)  t++;       // even tile, stages t+1
    TILE_BODY(1, b0B, b0A)  t++;       // odd tile, stages t+1
  }
  TILE_BODY(0, b0A, b0B)  t++;         // tile nkt-2, stages nkt-1
  // tail: tile nkt-1 (buf 1), drain 4 -> 2 -> 0
  READ_A(1, 0)
  SB0 WVM2 BARR LGKM SB0
  MFMA16(0,0,b0B)
  READ_B(b1, 1, 1)
  SB0 WVM0 BARR LGKM SB0
  MFMA16(0,1,b1)
  READ_A(1, 1)
  SB0 BARR LGKM SB0
  MFMA16(1,1,b1)
  MFMA16(1,0,b0B)

  #pragma unroll
  for (int mi = 0; mi < 8; mi++){
    #pragma unroll
    for (int nj = 0; nj < 4; nj++){
      int col = wc*64 + nj*16 + lr;
      if (ncol + col < nvalid){
        float bv = bias ? bias[ncol + col] : 0.f;
        #pragma unroll
        for (int q = 0; q < 4; q++){
          long row = mrow + wr*128 + mi*16 + lh*4 + q;
          if (row < E_TOT)
            out[row*(long)TL + kbase + ncol + col] = acc[mi][nj][q] + bv;
        }
      }
    }
  }
}

extern "C" void kernel_launch(void* const* d_in, const int* in_sizes, int n_in,
                              void* d_out, int out_size, void* d_ws, size_t ws_size,
                              hipStream_t stream){
  (void)in_sizes; (void)n_in; (void)out_size;
  const float* x_emb  = (const float*)d_in[0];
  const float* x_edge = (const float*)d_in[1];
  const float* rad_w1 = (const float*)d_in[2];
  const float* rad_b1 = (const float*)d_in[3];
  const float* rad_g  = (const float*)d_in[4];
  const float* rad_bt = (const float*)d_in[5];
  const float* rad_w2 = (const float*)d_in[6];
  const float* rad_b2 = (const float*)d_in[7];
  const float* w_m0   = (const float*)d_in[8];
  const float* b_m0   = (const float*)d_in[9];
  const float* w_m1   = (const float*)d_in[10];
  const float* w_m2   = (const float*)d_in[11];
  float* out = (float*)d_out;
  char* ws = (char*)d_ws;

  // workspace layout (bytes, 16B-aligned)
  u16* t   = (u16*)(ws + 0);            // 30000*3712*2   = 222,720,000
  u16* rad = (u16*)(ws + 222720000);    // 30000*2304*2   = 138,240,000
  u16* h   = (u16*)(ws + 360960000);    // 30000*128*2    =   7,680,000
  u16* W0  = (u16*)(ws + 368640000);    // 1024*896*2     =   1,835,008
  u16* W1  = (u16*)(ws + 370475008);    // 1536*1536*2    =   4,718,592
  u16* W2  = (u16*)(ws + 375193600);    // 1280*1280*2    =   3,276,800
  if (ws_size < 378470400ull) return;

  k_build_w<<<dim3(19200), dim3(256), 0, stream>>>(w_m0, w_m1, w_m2, W0, W1, W2);
  k_h<<<dim3(1875), dim3(256), 0, stream>>>(x_edge, rad_w1, rad_b1, rad_g, rad_bt, h);
  k_rad<<<dim3(469, 36), dim3(256), 0, stream>>>(h, rad_w2, rad_b2, rad);
  k_t<<<dim3(54375), dim3(256), 0, stream>>>(x_emb, rad, t);
  k_gemm8<<<dim3(1770), dim3(512), 0, stream>>>(t, W0, W1, W2, b_m0, out);
}

// Round 5
// 871.171 us; speedup vs baseline: 1.1607x; 1.1607x over previous
//
#include <hip/hip_runtime.h>
#include <stdint.h>

typedef unsigned short u16;
typedef __attribute__((ext_vector_type(8))) short short8;
typedef __attribute__((ext_vector_type(8))) u16 u16x8;
typedef __attribute__((ext_vector_type(4))) u16 u16x4;
typedef __attribute__((ext_vector_type(4))) float f32x4;

#define E_TOT 30000
#define TL    3712     // 29*128
#define RADN  2304
#define BM    256
#define BK    64

// PERM: m-major reorder of the 29 (l,m) coefficients
__constant__ int d_PERM[29] = {0,2,6,11,16,21,26, 3,7,12,17,22,27, 1,5,10,15,20,25,
                               8,13,18,23,28, 4,9,14,19,24};
__constant__ int d_RADCOL[29] = {0,1,2,3,4,5,6, 7,8,9,10,11,12, 7,8,9,10,11,12,
                                 13,14,15,16,17, 13,14,15,16,17};

__device__ __forceinline__ u16 f2bf(float f){
  union { float f; uint32_t u; } v; v.f = f;
  return (u16)((v.u + 0x7FFFu + ((v.u >> 16) & 1u)) >> 16);   // RNE
}
__device__ __forceinline__ float bf2f(u16 u){
  union { uint32_t u; float f; } v; v.u = ((uint32_t)u) << 16;
  return v.f;
}
__device__ __forceinline__ void gl_lds16(const void* g, void* l){
  __builtin_amdgcn_global_load_lds((const __attribute__((address_space(1))) void*)g,
                                   (__attribute__((address_space(3))) void*)l, 16, 0, 0);
}

// ---------------------------------------------------------------- weights
// w2b = bf16(rad_w2); W0 [1024][896] (zero-padded rows); W1/W2 folded butterfly
__global__ void k_build_w(const float* __restrict__ w0, const float* __restrict__ w1,
                          const float* __restrict__ w2, const float* __restrict__ rw2,
                          u16* __restrict__ W0, u16* __restrict__ W1, u16* __restrict__ W2,
                          u16* __restrict__ w2b){
  int idx = blockIdx.x * 256 + threadIdx.x;
  if (idx < 2304*128){ w2b[idx] = f2bf(rw2[idx]); return; }
  idx -= 2304*128;
  if (idx < 1024*896){
    W0[idx] = (idx < 896*896) ? f2bf(w0[idx]) : (u16)0;
    return;
  }
  idx -= 1024*896;
  if (idx < 1536*1536){
    const int half = 768;
    int o = idx / 1536, i2 = idx - o*1536;
    float v;
    if (o < half) v = (i2 < half) ? w1[o*half + i2] : -w1[(half+o)*half + (i2-half)];
    else { int op = o - half;
           v = (i2 < half) ? w1[(half+op)*half + i2] : w1[op*half + (i2-half)]; }
    W1[idx] = f2bf(v);
    return;
  }
  idx -= 1536*1536;
  if (idx < 1280*1280){
    const int half = 640;
    int o = idx / 1280, i2 = idx - o*1280;
    float v;
    if (o < half) v = (i2 < half) ? w2[o*half + i2] : -w2[(half+o)*half + (i2-half)];
    else { int op = o - half;
           v = (i2 < half) ? w2[(half+op)*half + i2] : w2[op*half + (i2-half)]; }
    W2[idx] = f2bf(v);
  }
}

// ---------------------------------------------------------------- h = silu(LN(xe@w1^T+b1))
__global__ __launch_bounds__(256) void k_h(const float* __restrict__ xe,
    const float* __restrict__ w1, const float* __restrict__ b1,
    const float* __restrict__ g, const float* __restrict__ beta,
    u16* __restrict__ hout){
  __shared__ float sxe[16*128];
  int tid = threadIdx.x;
  int eb = blockIdx.x * 16;
  #pragma unroll
  for (int q = 0; q < 2; q++){
    int off = q*1024 + tid*4;
    *(f32x4*)&sxe[off] = *(const f32x4*)&xe[(long)eb*128 + off];
  }
  __syncthreads();
  int el = tid >> 4, s = tid & 15;
  float acc[8];
  #pragma unroll
  for (int q = 0; q < 8; q++) acc[q] = 0.f;
  const float* xr = &sxe[el*128];
  for (int c4 = 0; c4 < 32; c4++){
    f32x4 x = *(const f32x4*)&xr[c4*4];
    #pragma unroll
    for (int q = 0; q < 8; q++){
      f32x4 w = *(const f32x4*)&w1[(s + 16*q)*128 + c4*4];
      acc[q] += x[0]*w[0] + x[1]*w[1] + x[2]*w[2] + x[3]*w[3];
    }
  }
  float sum = 0.f, ss = 0.f;
  #pragma unroll
  for (int q = 0; q < 8; q++){
    acc[q] += b1[s + 16*q];
    sum += acc[q]; ss += acc[q]*acc[q];
  }
  #pragma unroll
  for (int m = 1; m < 16; m <<= 1){ sum += __shfl_xor(sum, m); ss += __shfl_xor(ss, m); }
  float mu = sum * (1.f/128.f);
  float var = ss * (1.f/128.f) - mu*mu;
  float rs = rsqrtf(var + 1e-5f);
  int e = eb + el;
  #pragma unroll
  for (int q = 0; q < 8; q++){
    int j = s + 16*q;
    float v = (acc[q] - mu) * rs * g[j] + beta[j];
    v = v / (1.f + expf(-v));                 // silu
    hout[(long)e*128 + j] = f2bf(v);
  }
}

// ---------------------------------------------------------------- rad = h @ w2^T + b2 (bf16)
__global__ __launch_bounds__(256) void k_rad(const u16* __restrict__ h,
    const u16* __restrict__ w2b, const float* __restrict__ b2,
    u16* __restrict__ rad){
  __shared__ u16 sA[64*136];
  __shared__ u16 sB[64*136];
  int tid = threadIdx.x;
  int mb = blockIdx.x * 64, nb = blockIdx.y * 64;
  #pragma unroll
  for (int q = 0; q < 4; q++){
    int ch = q*256 + tid;
    int row = ch >> 4, col = (ch & 15) * 8;
    int er = mb + row; if (er > E_TOT-1) er = E_TOT-1;
    *(u16x8*)&sA[row*136 + col] = *(const u16x8*)&h[(long)er*128 + col];
  }
  #pragma unroll
  for (int q = 0; q < 4; q++){
    int ch = q*256 + tid;
    int row = ch >> 4, col = (ch & 15) * 8;
    *(u16x8*)&sB[row*136 + col] = *(const u16x8*)&w2b[(long)(nb + row)*128 + col];
  }
  __syncthreads();
  int wid = tid >> 6, l = tid & 63;
  int lr = l & 15, lh = l >> 4;
  f32x4 acc[4];
  #pragma unroll
  for (int mi = 0; mi < 4; mi++){ acc[mi][0]=0;acc[mi][1]=0;acc[mi][2]=0;acc[mi][3]=0; }
  #pragma unroll
  for (int kk = 0; kk < 4; kk++){
    int kc = kk*32 + lh*8;
    short8 b = *(short8*)&sB[(wid*16 + lr)*136 + kc];
    #pragma unroll
    for (int mi = 0; mi < 4; mi++){
      short8 a = *(short8*)&sA[(mi*16 + lr)*136 + kc];
      acc[mi] = __builtin_amdgcn_mfma_f32_16x16x32_bf16(a, b, acc[mi], 0, 0, 0);
    }
  }
  #pragma unroll
  for (int mi = 0; mi < 4; mi++){
    #pragma unroll
    for (int q = 0; q < 4; q++){
      int er = mb + mi*16 + lh*4 + q;
      if (er < E_TOT){
        int nc = nb + wid*16 + lr;
        rad[(long)er*RADN + nc] = f2bf(acc[mi][q] + b2[nc]);
      }
    }
  }
}

// ---------------------------------------------------------------- t[e, r*128+c] = xm * rad
__global__ void k_t(const float* __restrict__ xemb, const u16* __restrict__ rad,
                    u16* __restrict__ t){
  long idx = (long)blockIdx.x * 256 + threadIdx.x;   // one 8-elem chunk
  int c8 = (int)(idx & 15);
  long tmp = idx >> 4;
  int r = (int)(tmp % 29);
  int e = (int)(tmp / 29);
  if (e >= E_TOT) return;
  int c = c8 * 8;
  const float* xr = &xemb[((long)e*29 + d_PERM[r])*128 + c];
  const u16* rr = &rad[(long)e*RADN + d_RADCOL[r]*128 + c];
  f32x4 x0 = *(const f32x4*)xr;
  f32x4 x1 = *(const f32x4*)(xr + 4);
  u16x8 rv = *(const u16x8*)rr;
  u16x8 o;
  o[0]=f2bf(x0[0]*bf2f(rv[0])); o[1]=f2bf(x0[1]*bf2f(rv[1]));
  o[2]=f2bf(x0[2]*bf2f(rv[2])); o[3]=f2bf(x0[3]*bf2f(rv[3]));
  o[4]=f2bf(x1[0]*bf2f(rv[4])); o[5]=f2bf(x1[1]*bf2f(rv[5]));
  o[6]=f2bf(x1[2]*bf2f(rv[6])); o[7]=f2bf(x1[3]*bf2f(rv[7]));
  *(u16x8*)&t[idx*8] = o;
}

// ---------------------------------------------------------------- 256x256 GEMM, 2-sync/tile
#define WVM6 asm volatile("s_waitcnt vmcnt(6)" ::: "memory");
#define WVM2 asm volatile("s_waitcnt vmcnt(2)" ::: "memory");
#define WVM0 asm volatile("s_waitcnt vmcnt(0)" ::: "memory");
#define BARR __builtin_amdgcn_s_barrier();
#define SB0  __builtin_amdgcn_sched_barrier(0);

// read A-half QM into af (8 x ds_read_b128)
#define READ_A(buf, QM)                                                       \
  _Pragma("unroll")                                                           \
  for (int i = 0; i < 4; i++){                                                \
    _Pragma("unroll")                                                         \
    for (int ks = 0; ks < 2; ks++)                                            \
      af[i][ks] = *(const short8*)&S[buf][0][(wr*128 + (QM)*64 + i*16 + lr)*64\
                                            + ((ks*32 + lh*8) ^ swz)];        \
  }
// read B-half QN into dst (4 x ds_read_b128)
#define READ_B(dst, buf, QN)                                                  \
  _Pragma("unroll")                                                           \
  for (int j = 0; j < 2; j++){                                                \
    _Pragma("unroll")                                                         \
    for (int ks = 0; ks < 2; ks++)                                            \
      dst[j][ks] = *(const short8*)&S[buf][1][(wc*64 + (QN)*32 + j*16 + lr)*64\
                                              + ((ks*32 + lh*8) ^ swz)];      \
  }
// 16 MFMA for quadrant (QM,QN) using af x bfr
#define MFMA16(QM, QN, bfr)                                                   \
  __builtin_amdgcn_s_setprio(1);                                              \
  _Pragma("unroll")                                                           \
  for (int i = 0; i < 4; i++){                                                \
    _Pragma("unroll")                                                         \
    for (int j = 0; j < 2; j++){                                              \
      _Pragma("unroll")                                                       \
      for (int ks = 0; ks < 2; ks++)                                          \
        acc[(QM)*4+i][(QN)*2+j] = __builtin_amdgcn_mfma_f32_16x16x32_bf16(    \
            af[i][ks], bfr[j][ks], acc[(QM)*4+i][(QN)*2+j], 0, 0, 0);         \
    }                                                                         \
  }                                                                           \
  __builtin_amdgcn_s_setprio(0);

// staging: slots 0,1=B0  2,3=A0  4,5=B1  6,7=A1 (issue order == vmcnt order)
#define STAGE_EARLY(pn)                                                       \
  { _Pragma("unroll")                                                         \
    for (int k2 = 0; k2 < 6; k2++){                                           \
      gl_lds16(gsrc[k2], l0 + ((pn) << 15) + ldso[k2]);                       \
      gsrc[k2] += 64;                                                         \
    } }
#define STAGE_LATE(pn)                                                        \
  { _Pragma("unroll")                                                         \
    for (int k2 = 6; k2 < 8; k2++){                                           \
      gl_lds16(gsrc[k2], l0 + ((pn) << 15) + ldso[k2]);                       \
      gsrc[k2] += 64;                                                         \
    } }

// grid: 1770 blocks of 512 threads; 0..471 -> W0(K=896), 472..1179 -> W1(1536),
// 1180..1769 -> W2(1280). nbase == kbase for this problem.
__global__ __launch_bounds__(512, 2) void k_gemm8(
    const u16* __restrict__ A,
    const u16* __restrict__ W0, const u16* __restrict__ W1, const u16* __restrict__ W2,
    const float* __restrict__ bias0,
    float* __restrict__ out)
{
  __shared__ u16 S[2][2][BM*BK];   // [buf][A/B][256*64], swizzled (chunk ^= row&7)

  // bijective XCD swizzle over 1770 blocks, 8 XCDs (1770 = 8*221 + 2)
  int orig = blockIdx.x;
  int xcd = orig & 7, idxs = orig >> 3;
  int wgid = (xcd < 2 ? xcd*222 : 444 + (xcd-2)*221) + idxs;

  int ntn, K, kbase, nvalid, base;
  const u16* Wg; const float* bias = nullptr;
  if (wgid < 472)      { base=0;    ntn=4; K=896;  kbase=0;    nvalid=896;  Wg=W0; bias=bias0; }
  else if (wgid < 1180){ base=472;  ntn=6; K=1536; kbase=896;  nvalid=1536; Wg=W1; }
  else                 { base=1180; ntn=5; K=1280; kbase=2432; nvalid=1280; Wg=W2; }
  int local = wgid - base;
  int ncol = (local % ntn) * 256;
  int mrow = (local / ntn) * 256;
  int nkt  = K >> 6;

  int tid = threadIdx.x;
  int lane = tid & 63, wid = tid >> 6;
  int wr = wid >> 2, wc = wid & 3;     // wave grid 2(M) x 4(N); wave tile 128 x 64
  int lr = lane & 15, lh = lane >> 4;
  int swz = (lane & 7) << 3;           // read-side XOR (u16 units); row&7 == lane&7

  // hoisted staging addresses (per thread, advance +64 u16 per K-tile)
  const u16* gsrc[8];
  int ldso[8];
  u16* l0 = &S[0][0][0];
  #pragma unroll
  for (int j = 0; j < 2; j++){
    int CH = (wid*2 + j)*64 + lane;    // 1024 x 16B chunks per half-tile
    int c16 = CH & 7;
    int ra0 = ((CH >> 9) << 7) + ((CH >> 3) & 63);        // A0 rows {0-63,128-191}
    long g0 = mrow + ra0; if (g0 > (long)(E_TOT-1)) g0 = (long)(E_TOT-1);
    gsrc[2+j] = A + g0*(long)TL + kbase + ((c16 ^ (ra0 & 7)) << 3);
    ldso[2+j] = ra0*64 + c16*8;
    int ra1 = ra0 + 64;                                   // A1 rows {64-127,192-255}
    long g1 = mrow + ra1; if (g1 > (long)(E_TOT-1)) g1 = (long)(E_TOT-1);
    gsrc[6+j] = A + g1*(long)TL + kbase + ((c16 ^ (ra1 & 7)) << 3);
    ldso[6+j] = ra1*64 + c16*8;
    int rb0 = ((CH >> 8) << 6) + ((CH >> 3) & 31);        // B0 rows {+0..31 per 64-grp}
    gsrc[0+j] = Wg + (long)(ncol + rb0)*K + ((c16 ^ (rb0 & 7)) << 3);
    ldso[0+j] = 16384 + rb0*64 + c16*8;
    int rb1 = rb0 + 32;                                   // B1 rows {+32..63}
    gsrc[4+j] = Wg + (long)(ncol + rb1)*K + ((c16 ^ (rb1 & 7)) << 3);
    ldso[4+j] = 16384 + rb1*64 + c16*8;
  }

  f32x4 acc[8][4];
  #pragma unroll
  for (int i = 0; i < 8; i++)
    #pragma unroll
    for (int j = 0; j < 4; j++){ acc[i][j][0]=0;acc[i][j][1]=0;acc[i][j][2]=0;acc[i][j][3]=0; }

  short8 af[4][2];     // current A-half fragments
  short8 b0[2][2];     // B-half 0 (held across whole tile)
  short8 b1[2][2];     // B-half 1

  // prologue: stage tile 0 (B0,A0,B1 | A1) -> buf 0; retire first 6; read entry frags
  STAGE_EARLY(0)
  STAGE_LATE(0)
  WVM2 BARR SB0
  READ_A(0, 0)
  READ_B(b0, 0, 0)
  READ_B(b1, 0, 1)

  // steady state per tile: queue in = 2 (A1_t). Two sync points.
  for (int t = 0; t < nkt-1; ++t){
    int p = t & 1, pn = p ^ 1;
    STAGE_EARLY(pn)                   // B0,A0,B1 of t+1; queue 2 -> 8
    MFMA16(0,0,b0)
    MFMA16(0,1,b1)
    WVM6 BARR SB0                     // retire A1_t (cross-wave visible)
    READ_A(p, 1)
    STAGE_LATE(pn)                    // A1 of t+1; queue 6 -> 8
    MFMA16(1,1,b1)
    MFMA16(1,0,b0)
    WVM2 BARR SB0                     // retire B0,A0,B1 of t+1
    READ_A(pn, 0)
    READ_B(b0, pn, 0)
    READ_B(b1, pn, 1)
  }
  { // tail tile nkt-1 (buf p), queue in = 2 (its A1)
    int p = (nkt-1) & 1;
    MFMA16(0,0,b0)
    MFMA16(0,1,b1)
    WVM0 BARR SB0
    READ_A(p, 1)
    MFMA16(1,1,b1)
    MFMA16(1,0,b0)
  }

  #pragma unroll
  for (int mi = 0; mi < 8; mi++){
    #pragma unroll
    for (int nj = 0; nj < 4; nj++){
      int col = wc*64 + nj*16 + lr;
      if (ncol + col < nvalid){
        float bv = bias ? bias[ncol + col] : 0.f;
        #pragma unroll
        for (int q = 0; q < 4; q++){
          long row = mrow + wr*128 + mi*16 + lh*4 + q;
          if (row < E_TOT)
            out[row*(long)TL + kbase + ncol + col] = acc[mi][nj][q] + bv;
        }
      }
    }
  }
}

extern "C" void kernel_launch(void* const* d_in, const int* in_sizes, int n_in,
                              void* d_out, int out_size, void* d_ws, size_t ws_size,
                              hipStream_t stream){
  (void)in_sizes; (void)n_in; (void)out_size;
  const float* x_emb  = (const float*)d_in[0];
  const float* x_edge = (const float*)d_in[1];
  const float* rad_w1 = (const float*)d_in[2];
  const float* rad_b1 = (const float*)d_in[3];
  const float* rad_g  = (const float*)d_in[4];
  const float* rad_bt = (const float*)d_in[5];
  const float* rad_w2 = (const float*)d_in[6];
  const float* rad_b2 = (const float*)d_in[7];
  const float* w_m0   = (const float*)d_in[8];
  const float* b_m0   = (const float*)d_in[9];
  const float* w_m1   = (const float*)d_in[10];
  const float* w_m2   = (const float*)d_in[11];
  float* out = (float*)d_out;
  char* ws = (char*)d_ws;

  // workspace layout (bytes, 16B-aligned)
  u16* t   = (u16*)(ws + 0);            // 30000*3712*2   = 222,720,000
  u16* rad = (u16*)(ws + 222720000);    // 30000*2304*2   = 138,240,000
  u16* h   = (u16*)(ws + 360960000);    // 30000*128*2    =   7,680,000
  u16* W0  = (u16*)(ws + 368640000);    // 1024*896*2     =   1,835,008
  u16* W1  = (u16*)(ws + 370475008);    // 1536*1536*2    =   4,718,592
  u16* W2  = (u16*)(ws + 375193600);    // 1280*1280*2    =   3,276,800
  u16* w2b = (u16*)(ws + 378470400);    // 2304*128*2     =     589,824
  if (ws_size < 379060224ull) return;

  k_build_w<<<dim3(20352), dim3(256), 0, stream>>>(w_m0, w_m1, w_m2, rad_w2,
                                                   W0, W1, W2, w2b);
  k_h<<<dim3(1875), dim3(256), 0, stream>>>(x_edge, rad_w1, rad_b1, rad_g, rad_bt, h);
  k_rad<<<dim3(469, 36), dim3(256), 0, stream>>>(h, w2b, rad_b2, rad);
  k_t<<<dim3(54375), dim3(256), 0, stream>>>(x_emb, rad, t);
  k_gemm8<<<dim3(1770), dim3(512), 0, stream>>>(t, W0, W1, W2, b_m0, out);
}

// Round 6
// 862.924 us; speedup vs baseline: 1.1718x; 1.0096x over previous
//
#include <hip/hip_runtime.h>
#include <stdint.h>

typedef unsigned short u16;
typedef __attribute__((ext_vector_type(8))) short short8;
typedef __attribute__((ext_vector_type(8))) u16 u16x8;
typedef __attribute__((ext_vector_type(4))) u16 u16x4;
typedef __attribute__((ext_vector_type(4))) float f32x4;

#define E_TOT 30000
#define TL    3712     // 29*128
#define RADN  2304
#define BM    256
#define BK    64

// PERM: m-major reorder of the 29 (l,m) coefficients
__constant__ int d_PERM[29] = {0,2,6,11,16,21,26, 3,7,12,17,22,27, 1,5,10,15,20,25,
                               8,13,18,23,28, 4,9,14,19,24};
__constant__ int d_RADCOL[29] = {0,1,2,3,4,5,6, 7,8,9,10,11,12, 7,8,9,10,11,12,
                                 13,14,15,16,17, 13,14,15,16,17};

__device__ __forceinline__ u16 f2bf(float f){
  union { float f; uint32_t u; } v; v.f = f;
  return (u16)((v.u + 0x7FFFu + ((v.u >> 16) & 1u)) >> 16);   // RNE
}
__device__ __forceinline__ float bf2f(u16 u){
  union { uint32_t u; float f; } v; v.u = ((uint32_t)u) << 16;
  return v.f;
}
__device__ __forceinline__ void gl_lds16(const void* g, void* l){
  __builtin_amdgcn_global_load_lds((const __attribute__((address_space(1))) void*)g,
                                   (__attribute__((address_space(3))) void*)l, 16, 0, 0);
}

// ---------------------------------------------------------------- weights
// w2b = bf16(rad_w2); W0 [1024][896] (zero-padded rows); W1/W2 folded butterfly
__global__ void k_build_w(const float* __restrict__ w0, const float* __restrict__ w1,
                          const float* __restrict__ w2, const float* __restrict__ rw2,
                          u16* __restrict__ W0, u16* __restrict__ W1, u16* __restrict__ W2,
                          u16* __restrict__ w2b){
  int idx = blockIdx.x * 256 + threadIdx.x;
  if (idx < 2304*128){ w2b[idx] = f2bf(rw2[idx]); return; }
  idx -= 2304*128;
  if (idx < 1024*896){
    W0[idx] = (idx < 896*896) ? f2bf(w0[idx]) : (u16)0;
    return;
  }
  idx -= 1024*896;
  if (idx < 1536*1536){
    const int half = 768;
    int o = idx / 1536, i2 = idx - o*1536;
    float v;
    if (o < half) v = (i2 < half) ? w1[o*half + i2] : -w1[(half+o)*half + (i2-half)];
    else { int op = o - half;
           v = (i2 < half) ? w1[(half+op)*half + i2] : w1[op*half + (i2-half)]; }
    W1[idx] = f2bf(v);
    return;
  }
  idx -= 1536*1536;
  if (idx < 1280*1280){
    const int half = 640;
    int o = idx / 1280, i2 = idx - o*1280;
    float v;
    if (o < half) v = (i2 < half) ? w2[o*half + i2] : -w2[(half+o)*half + (i2-half)];
    else { int op = o - half;
           v = (i2 < half) ? w2[(half+op)*half + i2] : w2[op*half + (i2-half)]; }
    W2[idx] = f2bf(v);
  }
}

// ---------------------------------------------------------------- h = silu(LN(xe@w1^T+b1))
__global__ __launch_bounds__(256) void k_h(const float* __restrict__ xe,
    const float* __restrict__ w1, const float* __restrict__ b1,
    const float* __restrict__ g, const float* __restrict__ beta,
    u16* __restrict__ hout){
  __shared__ float sxe[16*128];
  int tid = threadIdx.x;
  int eb = blockIdx.x * 16;
  #pragma unroll
  for (int q = 0; q < 2; q++){
    int off = q*1024 + tid*4;
    *(f32x4*)&sxe[off] = *(const f32x4*)&xe[(long)eb*128 + off];
  }
  __syncthreads();
  int el = tid >> 4, s = tid & 15;
  float acc[8];
  #pragma unroll
  for (int q = 0; q < 8; q++) acc[q] = 0.f;
  const float* xr = &sxe[el*128];
  for (int c4 = 0; c4 < 32; c4++){
    f32x4 x = *(const f32x4*)&xr[c4*4];
    #pragma unroll
    for (int q = 0; q < 8; q++){
      f32x4 w = *(const f32x4*)&w1[(s + 16*q)*128 + c4*4];
      acc[q] += x[0]*w[0] + x[1]*w[1] + x[2]*w[2] + x[3]*w[3];
    }
  }
  float sum = 0.f, ss = 0.f;
  #pragma unroll
  for (int q = 0; q < 8; q++){
    acc[q] += b1[s + 16*q];
    sum += acc[q]; ss += acc[q]*acc[q];
  }
  #pragma unroll
  for (int m = 1; m < 16; m <<= 1){ sum += __shfl_xor(sum, m); ss += __shfl_xor(ss, m); }
  float mu = sum * (1.f/128.f);
  float var = ss * (1.f/128.f) - mu*mu;
  float rs = rsqrtf(var + 1e-5f);
  int e = eb + el;
  #pragma unroll
  for (int q = 0; q < 8; q++){
    int j = s + 16*q;
    float v = (acc[q] - mu) * rs * g[j] + beta[j];
    v = v / (1.f + expf(-v));                 // silu
    hout[(long)e*128 + j] = f2bf(v);
  }
}

// ---------------------------------------------------------------- rad = h @ w2^T + b2 (bf16)
__global__ __launch_bounds__(256) void k_rad(const u16* __restrict__ h,
    const u16* __restrict__ w2b, const float* __restrict__ b2,
    u16* __restrict__ rad){
  __shared__ u16 sA[64*136];
  __shared__ u16 sB[64*136];
  int tid = threadIdx.x;
  int mb = blockIdx.x * 64, nb = blockIdx.y * 64;
  #pragma unroll
  for (int q = 0; q < 4; q++){
    int ch = q*256 + tid;
    int row = ch >> 4, col = (ch & 15) * 8;
    int er = mb + row; if (er > E_TOT-1) er = E_TOT-1;
    *(u16x8*)&sA[row*136 + col] = *(const u16x8*)&h[(long)er*128 + col];
  }
  #pragma unroll
  for (int q = 0; q < 4; q++){
    int ch = q*256 + tid;
    int row = ch >> 4, col = (ch & 15) * 8;
    *(u16x8*)&sB[row*136 + col] = *(const u16x8*)&w2b[(long)(nb + row)*128 + col];
  }
  __syncthreads();
  int wid = tid >> 6, l = tid & 63;
  int lr = l & 15, lh = l >> 4;
  f32x4 acc[4];
  #pragma unroll
  for (int mi = 0; mi < 4; mi++){ acc[mi][0]=0;acc[mi][1]=0;acc[mi][2]=0;acc[mi][3]=0; }
  #pragma unroll
  for (int kk = 0; kk < 4; kk++){
    int kc = kk*32 + lh*8;
    short8 b = *(short8*)&sB[(wid*16 + lr)*136 + kc];
    #pragma unroll
    for (int mi = 0; mi < 4; mi++){
      short8 a = *(short8*)&sA[(mi*16 + lr)*136 + kc];
      acc[mi] = __builtin_amdgcn_mfma_f32_16x16x32_bf16(a, b, acc[mi], 0, 0, 0);
    }
  }
  #pragma unroll
  for (int mi = 0; mi < 4; mi++){
    #pragma unroll
    for (int q = 0; q < 4; q++){
      int er = mb + mi*16 + lh*4 + q;
      if (er < E_TOT){
        int nc = nb + wid*16 + lr;
        rad[(long)er*RADN + nc] = f2bf(acc[mi][q] + b2[nc]);
      }
    }
  }
}

// ---------------------------------------------------------------- t[e, r*128+c] = xm * rad
__global__ void k_t(const float* __restrict__ xemb, const u16* __restrict__ rad,
                    u16* __restrict__ t){
  long idx = (long)blockIdx.x * 256 + threadIdx.x;   // one 8-elem chunk
  int c8 = (int)(idx & 15);
  long tmp = idx >> 4;
  int r = (int)(tmp % 29);
  int e = (int)(tmp / 29);
  if (e >= E_TOT) return;
  int c = c8 * 8;
  const float* xr = &xemb[((long)e*29 + d_PERM[r])*128 + c];
  const u16* rr = &rad[(long)e*RADN + d_RADCOL[r]*128 + c];
  f32x4 x0 = *(const f32x4*)xr;
  f32x4 x1 = *(const f32x4*)(xr + 4);
  u16x8 rv = *(const u16x8*)rr;
  u16x8 o;
  o[0]=f2bf(x0[0]*bf2f(rv[0])); o[1]=f2bf(x0[1]*bf2f(rv[1]));
  o[2]=f2bf(x0[2]*bf2f(rv[2])); o[3]=f2bf(x0[3]*bf2f(rv[3]));
  o[4]=f2bf(x1[0]*bf2f(rv[4])); o[5]=f2bf(x1[1]*bf2f(rv[5]));
  o[6]=f2bf(x1[2]*bf2f(rv[6])); o[7]=f2bf(x1[3]*bf2f(rv[7]));
  *(u16x8*)&t[idx*8] = o;
}

// ---------------------------------------------------------------- 256x256 GEMM, true 8-phase
// 2-tile-deep pipeline: during tile t (reading buf p), stage into buf p's freed
// regions (data for t+2) and buf p^1's A1 (for t+1). 7 halves (14 loads/thread)
// in flight; ONE vmcnt(6) per tile at P4 retiring all of tile t+1.
#define WVM6 asm volatile("s_waitcnt vmcnt(6)" ::: "memory");
#define WVM0 asm volatile("s_waitcnt vmcnt(0)" ::: "memory");
#define BARR __builtin_amdgcn_s_barrier();
#define SB0  __builtin_amdgcn_sched_barrier(0);
#define LG0  asm volatile("s_waitcnt lgkmcnt(0)" ::: "memory");

// read A-half QM into af (8 x ds_read_b128)
#define READ_A(buf, QM)                                                       \
  _Pragma("unroll")                                                           \
  for (int i = 0; i < 4; i++){                                                \
    _Pragma("unroll")                                                         \
    for (int ks = 0; ks < 2; ks++)                                            \
      af[i][ks] = *(const short8*)&S[buf][0][(wr*128 + (QM)*64 + i*16 + lr)*64\
                                            + ((ks*32 + lh*8) ^ swz)];        \
  }
// read B-half QN into dst (4 x ds_read_b128)
#define READ_B(dst, buf, QN)                                                  \
  _Pragma("unroll")                                                           \
  for (int j = 0; j < 2; j++){                                                \
    _Pragma("unroll")                                                         \
    for (int ks = 0; ks < 2; ks++)                                            \
      dst[j][ks] = *(const short8*)&S[buf][1][(wc*64 + (QN)*32 + j*16 + lr)*64\
                                              + ((ks*32 + lh*8) ^ swz)];      \
  }
// 16 MFMA for quadrant (QM,QN) using af x bfr
#define MFMA16(QM, QN, bfr)                                                   \
  __builtin_amdgcn_s_setprio(1);                                              \
  _Pragma("unroll")                                                           \
  for (int i = 0; i < 4; i++){                                                \
    _Pragma("unroll")                                                         \
    for (int j = 0; j < 2; j++){                                              \
      _Pragma("unroll")                                                       \
      for (int ks = 0; ks < 2; ks++)                                          \
        acc[(QM)*4+i][(QN)*2+j] = __builtin_amdgcn_mfma_f32_16x16x32_bf16(    \
            af[i][ks], bfr[j][ks], acc[(QM)*4+i][(QN)*2+j], 0, 0, 0);         \
    }                                                                         \
  }                                                                           \
  __builtin_amdgcn_s_setprio(0);

// stage one half-tile: slot 0=A0, 1=B0, 2=B1, 3=A1 (2 gl_lds/thread)
#define STG(slot, bufi)                                                       \
  { _Pragma("unroll")                                                         \
    for (int j = 0; j < 2; j++){                                              \
      gl_lds16(gsrc[(slot)*2+j], l0 + ((bufi) << 15) + ldso[(slot)*2+j]);     \
      gsrc[(slot)*2+j] += 64;                                                 \
    } }

// grid: 1770 blocks of 512 threads; 0..471 -> W0(K=896), 472..1179 -> W1(1536),
// 1180..1769 -> W2(1280). nbase == kbase for this problem.
__global__ __launch_bounds__(512, 2) void k_gemm8(
    const u16* __restrict__ A,
    const u16* __restrict__ W0, const u16* __restrict__ W1, const u16* __restrict__ W2,
    const float* __restrict__ bias0,
    float* __restrict__ out)
{
  __shared__ u16 S[2][2][BM*BK];   // [buf][A/B][256*64], swizzled (chunk ^= row&7)

  // bijective XCD swizzle over 1770 blocks, 8 XCDs (1770 = 8*221 + 2)
  int orig = blockIdx.x;
  int xcd = orig & 7, idxs = orig >> 3;
  int wgid = (xcd < 2 ? xcd*222 : 444 + (xcd-2)*221) + idxs;

  int ntn, K, kbase, nvalid, base;
  const u16* Wg; const float* bias = nullptr;
  if (wgid < 472)      { base=0;    ntn=4; K=896;  kbase=0;    nvalid=896;  Wg=W0; bias=bias0; }
  else if (wgid < 1180){ base=472;  ntn=6; K=1536; kbase=896;  nvalid=1536; Wg=W1; }
  else                 { base=1180; ntn=5; K=1280; kbase=2432; nvalid=1280; Wg=W2; }
  int local = wgid - base;
  int ncol = (local % ntn) * 256;
  int mrow = (local / ntn) * 256;
  int nkt  = K >> 6;

  int tid = threadIdx.x;
  int lane = tid & 63, wid = tid >> 6;
  int wr = wid >> 2, wc = wid & 3;     // wave grid 2(M) x 4(N); wave tile 128 x 64
  int lr = lane & 15, lh = lane >> 4;
  int swz = (lane & 7) << 3;           // read-side XOR (u16 units); row&7 == lane&7

  // hoisted staging addresses (per thread, advance +64 u16 per staged tile)
  const u16* gsrc[8];
  int ldso[8];
  u16* l0 = &S[0][0][0];
  #pragma unroll
  for (int j = 0; j < 2; j++){
    int CH = (wid*2 + j)*64 + lane;    // 1024 x 16B chunks per half-tile
    int c16 = CH & 7;
    int ra0 = ((CH >> 9) << 7) + ((CH >> 3) & 63);        // A0 rows {0-63,128-191}
    long g0 = mrow + ra0; if (g0 > (long)(E_TOT-1)) g0 = (long)(E_TOT-1);
    gsrc[0+j] = A + g0*(long)TL + kbase + ((c16 ^ (ra0 & 7)) << 3);
    ldso[0+j] = ra0*64 + c16*8;
    int ra1 = ra0 + 64;                                   // A1 rows {64-127,192-255}
    long g1 = mrow + ra1; if (g1 > (long)(E_TOT-1)) g1 = (long)(E_TOT-1);
    gsrc[6+j] = A + g1*(long)TL + kbase + ((c16 ^ (ra1 & 7)) << 3);
    ldso[6+j] = ra1*64 + c16*8;
    int rb0 = ((CH >> 8) << 6) + ((CH >> 3) & 31);        // B0 rows {+0..31 per 64-grp}
    gsrc[2+j] = Wg + (long)(ncol + rb0)*K + ((c16 ^ (rb0 & 7)) << 3);
    ldso[2+j] = 16384 + rb0*64 + c16*8;
    int rb1 = rb0 + 32;                                   // B1 rows {+32..63}
    gsrc[4+j] = Wg + (long)(ncol + rb1)*K + ((c16 ^ (rb1 & 7)) << 3);
    ldso[4+j] = 16384 + rb1*64 + c16*8;
  }

  f32x4 acc[8][4];
  #pragma unroll
  for (int i = 0; i < 8; i++)
    #pragma unroll
    for (int j = 0; j < 4; j++){ acc[i][j][0]=0;acc[i][j][1]=0;acc[i][j][2]=0;acc[i][j][3]=0; }

  short8 af[4][2];     // current A-half fragments
  short8 b0[2][2];     // B-half 0 (held across whole tile)
  short8 b1[2][2];     // B-half 1

  // prologue: tile0 (A0,B0,B1,A1 -> buf0) + tile1 (A0,B0,B1 -> buf1); 14 loads.
  // vmcnt(6) retires tile0's 8; leaves tile1's 6 in flight.
  STG(0,0) STG(1,0) STG(2,0) STG(3,0)
  STG(0,1) STG(1,1) STG(2,1)
  WVM6
  BARR SB0

  // main loop: tiles 0..nkt-3 with full staging
  for (int t = 0; t < nkt-2; ++t){
    int p = t & 1;
    // P1: Q(0,0); reads A0,B0(t); stages A1 of t+1 -> buf p^1
    READ_A(p, 0)
    READ_B(b0, p, 0)
    STG(3, p^1)
    SB0 BARR LG0 SB0
    MFMA16(0,0,b0)
    BARR
    // P2: Q(0,1); reads B1(t); stages A0 of t+2 -> buf p (region freed at P1)
    READ_B(b1, p, 1)
    STG(0, p)
    SB0 BARR LG0 SB0
    MFMA16(0,1,b1)
    BARR
    // P3: Q(1,1); reads A1(t); stages B0 of t+2 -> buf p
    READ_A(p, 1)
    STG(1, p)
    SB0 BARR LG0 SB0
    MFMA16(1,1,b1)
    BARR
    // P4: Q(1,0); stages B1 of t+2 -> buf p; ONE vmcnt: retire all of tile t+1
    STG(2, p)
    WVM6
    SB0 BARR LG0 SB0
    MFMA16(1,0,b0)
    BARR
  }
  { // tile nkt-2: stage only A1 of nkt-1; P4 drains everything
    int p = (nkt-2) & 1;
    READ_A(p, 0)
    READ_B(b0, p, 0)
    STG(3, p^1)
    SB0 BARR LG0 SB0
    MFMA16(0,0,b0)
    BARR
    READ_B(b1, p, 1)
    SB0 BARR LG0 SB0
    MFMA16(0,1,b1)
    BARR
    READ_A(p, 1)
    SB0 BARR LG0 SB0
    MFMA16(1,1,b1)
    BARR
    WVM0
    SB0 BARR LG0 SB0
    MFMA16(1,0,b0)
    BARR
  }
  { // tile nkt-1: all resident; no staging, no vm waits
    int p = (nkt-1) & 1;
    READ_A(p, 0)
    READ_B(b0, p, 0)
    SB0 BARR LG0 SB0
    MFMA16(0,0,b0)
    BARR
    READ_B(b1, p, 1)
    SB0 BARR LG0 SB0
    MFMA16(0,1,b1)
    BARR
    READ_A(p, 1)
    SB0 BARR LG0 SB0
    MFMA16(1,1,b1)
    MFMA16(1,0,b0)
  }

  #pragma unroll
  for (int mi = 0; mi < 8; mi++){
    #pragma unroll
    for (int nj = 0; nj < 4; nj++){
      int col = wc*64 + nj*16 + lr;
      if (ncol + col < nvalid){
        float bv = bias ? bias[ncol + col] : 0.f;
        #pragma unroll
        for (int q = 0; q < 4; q++){
          long row = mrow + wr*128 + mi*16 + lh*4 + q;
          if (row < E_TOT)
            out[row*(long)TL + kbase + ncol + col] = acc[mi][nj][q] + bv;
        }
      }
    }
  }
}

extern "C" void kernel_launch(void* const* d_in, const int* in_sizes, int n_in,
                              void* d_out, int out_size, void* d_ws, size_t ws_size,
                              hipStream_t stream){
  (void)in_sizes; (void)n_in; (void)out_size;
  const float* x_emb  = (const float*)d_in[0];
  const float* x_edge = (const float*)d_in[1];
  const float* rad_w1 = (const float*)d_in[2];
  const float* rad_b1 = (const float*)d_in[3];
  const float* rad_g  = (const float*)d_in[4];
  const float* rad_bt = (const float*)d_in[5];
  const float* rad_w2 = (const float*)d_in[6];
  const float* rad_b2 = (const float*)d_in[7];
  const float* w_m0   = (const float*)d_in[8];
  const float* b_m0   = (const float*)d_in[9];
  const float* w_m1   = (const float*)d_in[10];
  const float* w_m2   = (const float*)d_in[11];
  float* out = (float*)d_out;
  char* ws = (char*)d_ws;

  // workspace layout (bytes, 16B-aligned)
  u16* t   = (u16*)(ws + 0);            // 30000*3712*2   = 222,720,000
  u16* rad = (u16*)(ws + 222720000);    // 30000*2304*2   = 138,240,000
  u16* h   = (u16*)(ws + 360960000);    // 30000*128*2    =   7,680,000
  u16* W0  = (u16*)(ws + 368640000);    // 1024*896*2     =   1,835,008
  u16* W1  = (u16*)(ws + 370475008);    // 1536*1536*2    =   4,718,592
  u16* W2  = (u16*)(ws + 375193600);    // 1280*1280*2    =   3,276,800
  u16* w2b = (u16*)(ws + 378470400);    // 2304*128*2     =     589,824
  if (ws_size < 379060224ull) return;

  k_build_w<<<dim3(20352), dim3(256), 0, stream>>>(w_m0, w_m1, w_m2, rad_w2,
                                                   W0, W1, W2, w2b);
  k_h<<<dim3(1875), dim3(256), 0, stream>>>(x_edge, rad_w1, rad_b1, rad_g, rad_bt, h);
  k_rad<<<dim3(469, 36), dim3(256), 0, stream>>>(h, w2b, rad_b2, rad);
  k_t<<<dim3(54375), dim3(256), 0, stream>>>(x_emb, rad, t);
  k_gemm8<<<dim3(1770), dim3(512), 0, stream>>>(t, W0, W1, W2, b_m0, out);
}